// Round 5
// baseline (942.910 us; speedup 1.0000x reference)
//
#include <hip/hip_runtime.h>
#include <math.h>

#define BB 32
#define CC 3
#define HH 224
#define WW 224
#define HWS (HH*WW)            // 50176
#define NELEM (BB*CC*HWS)      // 4,816,896
#define NTAPS (9*HWS)          // 451,584
#define EPS_IN 1e-5f
#define LNUM 10

#define NCHUNK (HWS/256)       // 196 chunks of 256 pixels
#define NBLK (NCHUNK*8)        // 1568 blocks (8 batch groups of 4 images)
#define PSTR 12                // floats per pixel per group: 3c x 4b

__device__ __forceinline__ float fast_tanh(float z) {
    z = fminf(fmaxf(z, -15.f), 15.f);
    float e = __expf(2.f * z);
    return (e - 1.f) * __frcp_rn(e + 1.f);
}

// ---------------- zero stats ----------------
__global__ void zero_kernel(float* __restrict__ p, int n) {
    int i = blockIdx.x * 256 + threadIdx.x;
    if (i < n) p[i] = 0.f;
}

// ------- precompute expanded taps: clamped flat idx + masked weights ------
__global__ __launch_bounds__(256) void taps_kernel(
    const float* __restrict__ off,   // [18,H,W] batch-0 offset plane
    int4* __restrict__ ti, float4* __restrict__ tw)
{
    int gid = blockIdx.x * 256 + threadIdx.x;    // k*HWS + pix, grid exact
    int k = gid / HWS, pix = gid - k * HWS;
    int h = pix / WW, wc = pix - h * WW;
    int ky = k / 3, kx = k - 3 * ky;
    float dy = off[(2 * k)     * HWS + pix];
    float dx = off[(2 * k + 1) * HWS + pix];
    float py = (float)(h  + ky - 1) + dy;
    float px = (float)(wc + kx - 1) + dx;
    float y0f = floorf(py), x0f = floorf(px);
    float wy = py - y0f, wx = px - x0f;
    int iy0 = (int)y0f, ix0 = (int)x0f;
    int iy1 = iy0 + 1,  ix1 = ix0 + 1;
    float vy0 = (iy0 >= 0 && iy0 < HH) ? 1.f : 0.f;
    float vy1 = (iy1 >= 0 && iy1 < HH) ? 1.f : 0.f;
    float vx0 = (ix0 >= 0 && ix0 < WW) ? 1.f : 0.f;
    float vx1 = (ix1 >= 0 && ix1 < WW) ? 1.f : 0.f;
    int cy0 = min(max(iy0, 0), HH - 1), cy1 = min(max(iy1, 0), HH - 1);
    int cx0 = min(max(ix0, 0), WW - 1), cx1 = min(max(ix1, 0), WW - 1);
    int4 ii;
    ii.x = cy0 * WW + cx0; ii.y = cy0 * WW + cx1;
    ii.z = cy1 * WW + cx0; ii.w = cy1 * WW + cx1;
    float4 ww;
    ww.x = (1.f - wy) * (1.f - wx) * vy0 * vx0;
    ww.y = (1.f - wy) * wx         * vy0 * vx1;
    ww.z = wy         * (1.f - wx) * vy1 * vx0;
    ww.w = wy         * wx         * vy1 * vx1;
    ti[gid] = ii; tw[gid] = ww;
}

// ------- [B,C,H,W] -> interleaved [g][HW][c][4] (b = g*4+j) ---------------
__global__ __launch_bounds__(256) void tin_kernel(
    const float* __restrict__ x, float* __restrict__ xI)
{
    int p = blockIdx.x;                  // 1568
    int g = p & 7, chunk = p >> 3;
    int pix = chunk * 256 + threadIdx.x;
    float4 v[3];
    #pragma unroll
    for (int c = 0; c < 3; ++c)
        #pragma unroll
        for (int j = 0; j < 4; ++j)
            ((float*)&v[c])[j] = x[((size_t)((g * 4 + j) * 3 + c)) * HWS + pix];
    float* dst = xI + ((size_t)g * HWS + pix) * PSTR;
    *(float4*)(dst + 0) = v[0];
    *(float4*)(dst + 4) = v[1];
    *(float4*)(dst + 8) = v[2];
}

// ---------------- deformable conv (+stats), interleaved layout ------------
// Thread = (pixel, batch-group of 4). One float4 gather serves 4 images; the
// 3 channels of a corner are 48 contiguous bytes. XCD swizzle: each XCD owns
// a contiguous pixel range for all groups (x slice 2.4MB + taps 1.8MB ~ L2).
__global__ __launch_bounds__(256) void conv_kernel(
    const float* __restrict__ xI,    // [8][HW][3][4]
    const int4*  __restrict__ ti,    // [9,HW]
    const float4* __restrict__ tw,   // [9,HW]
    const float* __restrict__ wt,    // [3,3,9] = [o][c][k]
    float* __restrict__ yI,          // [8][HW][3][4]
    float* __restrict__ stats)       // [B*3][2]
{
    __shared__ float w2[108];        // [k][o][c] padded to 4
    __shared__ float red[4][24];
    int t = threadIdx.x;
    if (t < 108) {
        int k = t / 12, r = t % 12, o = r >> 2, c = r & 3;
        w2[t] = (c < 3) ? wt[o * 27 + c * 9 + k] : 0.f;
    }
    __syncthreads();

    int p = blockIdx.x;
    int xcd = p & 7, i = p >> 3;
    int l = xcd * (NBLK / 8) + i;    // XCD-contiguous logical id
    int chunk = l >> 3, g = l & 7;
    int pix = chunk * 256 + t;

    const float* xg = xI + (size_t)g * HWS * PSTR;
    float4 a0 = make_float4(0.f, 0.f, 0.f, 0.f), a1 = a0, a2 = a0;

    #pragma unroll 3
    for (int k = 0; k < 9; ++k) {
        int4   ii = ti[k * HWS + pix];
        float4 ww = tw[k * HWS + pix];
        const float* p00 = xg + (size_t)ii.x * PSTR;
        const float* p01 = xg + (size_t)ii.y * PSTR;
        const float* p10 = xg + (size_t)ii.z * PSTR;
        const float* p11 = xg + (size_t)ii.w * PSTR;
        float4 wo0 = *(const float4*)&w2[k * 12 + 0];
        float4 wo1 = *(const float4*)&w2[k * 12 + 4];
        float4 wo2 = *(const float4*)&w2[k * 12 + 8];
        #pragma unroll
        for (int c = 0; c < 3; ++c) {
            float4 v00 = *(const float4*)(p00 + c * 4);
            float4 v01 = *(const float4*)(p01 + c * 4);
            float4 v10 = *(const float4*)(p10 + c * 4);
            float4 v11 = *(const float4*)(p11 + c * 4);
            float4 s;
            s.x = v00.x*ww.x + v01.x*ww.y + v10.x*ww.z + v11.x*ww.w;
            s.y = v00.y*ww.x + v01.y*ww.y + v10.y*ww.z + v11.y*ww.w;
            s.z = v00.z*ww.x + v01.z*ww.y + v10.z*ww.z + v11.z*ww.w;
            s.w = v00.w*ww.x + v01.w*ww.y + v10.w*ww.z + v11.w*ww.w;
            float c0 = ((const float*)&wo0)[c];
            float c1 = ((const float*)&wo1)[c];
            float c2 = ((const float*)&wo2)[c];
            a0.x = fmaf(s.x, c0, a0.x); a0.y = fmaf(s.y, c0, a0.y);
            a0.z = fmaf(s.z, c0, a0.z); a0.w = fmaf(s.w, c0, a0.w);
            a1.x = fmaf(s.x, c1, a1.x); a1.y = fmaf(s.y, c1, a1.y);
            a1.z = fmaf(s.z, c1, a1.z); a1.w = fmaf(s.w, c1, a1.w);
            a2.x = fmaf(s.x, c2, a2.x); a2.y = fmaf(s.y, c2, a2.y);
            a2.z = fmaf(s.z, c2, a2.z); a2.w = fmaf(s.w, c2, a2.w);
        }
    }

    float* yb = yI + ((size_t)g * HWS + pix) * PSTR;
    *(float4*)(yb + 0) = a0;
    *(float4*)(yb + 4) = a1;
    *(float4*)(yb + 8) = a2;

    // ---- per-(b,c) sum / sumsq: v[c*8 + j*2 + which] ----
    float v[24];
    #pragma unroll
    for (int j = 0; j < 4; ++j) {
        float e0 = ((float*)&a0)[j], e1 = ((float*)&a1)[j], e2 = ((float*)&a2)[j];
        v[0*8 + j*2 + 0] = e0; v[0*8 + j*2 + 1] = e0 * e0;
        v[1*8 + j*2 + 0] = e1; v[1*8 + j*2 + 1] = e1 * e1;
        v[2*8 + j*2 + 0] = e2; v[2*8 + j*2 + 1] = e2 * e2;
    }
    #pragma unroll
    for (int j = 0; j < 24; ++j)
        #pragma unroll
        for (int o = 1; o <= 32; o <<= 1)
            v[j] += __shfl_xor(v[j], o);
    int lane = t & 63, wv = t >> 6;
    if (lane == 0)
        #pragma unroll
        for (int j = 0; j < 24; ++j) red[wv][j] = v[j];
    __syncthreads();
    if (t < 24) {
        float sum = red[0][t] + red[1][t] + red[2][t] + red[3][t];
        int c = t / 8, r = t % 8, j = r >> 1, which = r & 1;
        int b = g * 4 + j;
        atomicAdd(&stats[(b * 3 + c) * 2 + which], sum);
    }
}

// ------------- instance norm + tanh, interleaved, in-place ----------------
__global__ __launch_bounds__(256) void norm_kernel(
    float* __restrict__ y, const float* __restrict__ stats,
    const float* __restrict__ gamma, const float* __restrict__ beta)
{
    int p = blockIdx.x;
    int xcd = p & 7, i = p >> 3;
    int l = xcd * (NBLK / 8) + i;
    int chunk = l >> 3, g = l & 7;
    int pix = chunk * 256 + threadIdx.x;
    float* base = y + ((size_t)g * HWS + pix) * PSTR;
    #pragma unroll
    for (int c = 0; c < 3; ++c) {
        float gc = gamma[c], bt = beta[c];
        float4 vv = *(float4*)(base + c * 4);
        #pragma unroll
        for (int j = 0; j < 4; ++j) {
            int b = g * 4 + j;
            float s = stats[(b * 3 + c) * 2 + 0];
            float q = stats[(b * 3 + c) * 2 + 1];
            float mean = s * (1.f / HWS);
            float var  = fmaxf(q * (1.f / HWS) - mean * mean, 0.f);
            float gs = gc * rsqrtf(var + EPS_IN);
            ((float*)&vv)[j] = fast_tanh((((float*)&vv)[j] - mean) * gs + bt);
        }
        *(float4*)(base + c * 4) = vv;
    }
}

// ------------- final: norm + tanh + write [B,C,H,W] -----------------------
__global__ __launch_bounds__(256) void norm_final_kernel(
    const float* __restrict__ y, const float* __restrict__ stats,
    const float* __restrict__ gamma, const float* __restrict__ beta,
    float* __restrict__ out)
{
    int p = blockIdx.x;
    int g = p & 7, chunk = p >> 3;
    int pix = chunk * 256 + threadIdx.x;
    const float* base = y + ((size_t)g * HWS + pix) * PSTR;
    #pragma unroll
    for (int c = 0; c < 3; ++c) {
        float gc = gamma[c], bt = beta[c];
        float4 vv = *(const float4*)(base + c * 4);
        #pragma unroll
        for (int j = 0; j < 4; ++j) {
            int b = g * 4 + j;
            float s = stats[(b * 3 + c) * 2 + 0];
            float q = stats[(b * 3 + c) * 2 + 1];
            float mean = s * (1.f / HWS);
            float var  = fmaxf(q * (1.f / HWS) - mean * mean, 0.f);
            float gs = gc * rsqrtf(var + EPS_IN);
            out[((size_t)(b * 3 + c)) * HWS + pix] =
                fast_tanh((((float*)&vv)[j] - mean) * gs + bt);
        }
    }
}

extern "C" void kernel_launch(void* const* d_in, const int* in_sizes, int n_in,
                              void* d_out, int out_size, void* d_ws, size_t ws_size,
                              hipStream_t stream) {
    const float* x     = (const float*)d_in[0];
    const float* wt    = (const float*)d_in[1];
    const float* off   = (const float*)d_in[2];   // batch-tiled -> plane 0
    const float* gamma = (const float*)d_in[3];
    const float* beta  = (const float*)d_in[4];

    float* out  = (float*)d_out;
    float* bufA = (float*)d_ws;
    float* bufB = bufA + NELEM;
    int4*  ti   = (int4*)(bufB + NELEM);
    float4* tw  = (float4*)((char*)ti + (size_t)NTAPS * 16);
    float* stats = (float*)((char*)tw + (size_t)NTAPS * 16);
    // ws: 2*19.27MB + 2*7.2MB + 7.7KB ~= 53 MB

    zero_kernel<<<(LNUM * 192 + 255) / 256, 256, 0, stream>>>(stats, LNUM * 192);
    taps_kernel<<<NTAPS / 256, 256, 0, stream>>>(off, ti, tw);
    tin_kernel<<<NBLK, 256, 0, stream>>>(x, bufA);

    float* cur = bufA;
    float* nxt = bufB;
    for (int it = 0; it < LNUM; ++it) {
        float* st = stats + it * 192;
        conv_kernel<<<NBLK, 256, 0, stream>>>(cur, ti, tw, wt, nxt, st);
        if (it < LNUM - 1)
            norm_kernel<<<NBLK, 256, 0, stream>>>(nxt, st, gamma, beta);
        else
            norm_final_kernel<<<NBLK, 256, 0, stream>>>(nxt, st, gamma, beta, out);
        float* tmp = cur; cur = nxt; nxt = tmp;
    }
}